// Round 1
// baseline (2205.841 us; speedup 1.0000x reference)
//
#include <hip/hip_runtime.h>

// ---------------------------------------------------------------------------
// KeyValueMemoryRecallNet: persistent weight-stationary MFMA recurrence.
// One wave (64 lanes) owns 16 batch elements for all 512 steps.
// Grid: 128 blocks x 64 threads (2048 batch / 16).
//
// MFMA 16x16x32 bf16 layouts (gfx950, guide-verified C/D):
//   A-frag: lane l holds A[row = l%16][k = 8*(l/16) + j], j=0..7
//   B-frag: lane l holds B[k = 8*(l/16) + j][col = l%16]
//   C/D   : lane l holds D[row = 4*(l/16) + r][col = l%16], r=0..3
// Any consistent k-permutation inside frags cancels between A and B.
// ---------------------------------------------------------------------------

typedef __attribute__((ext_vector_type(4))) float f32x4;
typedef __attribute__((ext_vector_type(8))) __bf16 bf16x8;

#define NB 2048
#define SL 512
#define NIN 64
#define NH 32
#define NO 16

__device__ __forceinline__ float sigmoidf_(float x) {
  return 1.0f / (1.0f + __expf(-x));
}
__device__ __forceinline__ float tanhf_(float x) {
  // tanh(x) = 1 - 2/(exp(2x)+1); robust at large |x| (inf -> 1 / 0 -> -1)
  return 1.0f - 2.0f / (__expf(2.0f * x) + 1.0f);
}
__device__ __forceinline__ f32x4 splat4(float v) {
  f32x4 r; r[0] = v; r[1] = v; r[2] = v; r[3] = v; return r;
}

// Build a bf16 B-fragment of W^T for output-tile rows [row] and k in [k0,k0+8).
// W is [outdim][indim] row-major; zero-fill past indim.
__device__ __forceinline__ bf16x8 ldfrag(const float* __restrict__ W, int indim,
                                         int row, int k0) {
  bf16x8 r;
#pragma unroll
  for (int j = 0; j < 8; ++j) {
    int k = k0 + j;
    float w = (k < indim) ? W[row * indim + k] : 0.0f;
    r[j] = (__bf16)w;
  }
  return r;
}

#define MFMA(A, B, C) __builtin_amdgcn_mfma_f32_16x16x32_bf16((A), (B), (C), 0, 0, 0)

__global__ __launch_bounds__(64, 1)
void kvmr_kernel(const float* __restrict__ inputs,   // [2048][512][64]
                 const float* __restrict__ w_ih,     // [96][66]
                 const float* __restrict__ w_hh,     // [96][32]
                 const float* __restrict__ b_ih,     // [96]
                 const float* __restrict__ b_hh,     // [96]
                 const float* __restrict__ W_key,    // [64][32]
                 const float* __restrict__ b_key,    // [64]
                 const float* __restrict__ W_query,  // [64][32]
                 const float* __restrict__ b_query,  // [64]
                 const float* __restrict__ W_value,  // [64][32]
                 const float* __restrict__ b_value,  // [64]
                 const float* __restrict__ W_recall, // [2][64]
                 const float* __restrict__ b_recall, // [2]
                 const float* __restrict__ W_out,    // [16][32]
                 const float* __restrict__ b_out,    // [16]
                 float* __restrict__ out_all) {      // outputs | hiddens
  const int l  = threadIdx.x;
  const int c  = l & 15;   // column lane (batch row for A, out-col for B/D)
  const int q4 = l >> 4;   // k-group / D row-group
  const int b0 = blockIdx.x * 16;

  // --- per-wave LDS: C-layout -> A-layout relay buffers (bf16) ---
  __shared__ __align__(16) __bf16 h_lds[16 * 32];   // h_new, rows=batch, cols=hidden
  __shared__ __align__(16) __bf16 x2_lds[16 * 32];  // [retr0, retr1, 0...] per row
  for (int i = l; i < 512; i += 64) {
    h_lds[i]  = (__bf16)0.0f;
    x2_lds[i] = (__bf16)0.0f;
  }
  __syncthreads();

  // --- stage all weights as register-resident B-fragments (once) ---
  bf16x8 Bih[6][3];  // gate tiles 0..5 (r0 r1 z0 z1 n0 n1), k-chunks x[0:32],x[32:64],[retr|0]
  bf16x8 Bhh[6];
#pragma unroll
  for (int g = 0; g < 6; ++g) {
#pragma unroll
    for (int kc = 0; kc < 3; ++kc)
      Bih[g][kc] = ldfrag(w_ih, 66, 16 * g + c, 32 * kc + 8 * q4);
    Bhh[g] = ldfrag(w_hh, 32, 16 * g + c, 8 * q4);
  }
  bf16x8 Bq[4], Bk[4], Bv[4];
#pragma unroll
  for (int g = 0; g < 4; ++g) {
    Bq[g] = ldfrag(W_query, 32, 16 * g + c, 8 * q4);
    Bk[g] = ldfrag(W_key,   32, 16 * g + c, 8 * q4);
    Bv[g] = ldfrag(W_value, 32, 16 * g + c, 8 * q4);
  }
  bf16x8 Bo = ldfrag(W_out, 32, c, 8 * q4);

  float wr0f[4], wr1f[4];
#pragma unroll
  for (int g = 0; g < 4; ++g) {
    wr0f[g] = W_recall[16 * g + c];
    wr1f[g] = W_recall[64 + 16 * g + c];
  }

  // --- biases (per-lane, col-indexed; same for all 4 D rows) ---
  float bias_rz[4], bias_xn[2], bias_hn[2];
#pragma unroll
  for (int g = 0; g < 4; ++g) bias_rz[g] = b_ih[16 * g + c] + b_hh[16 * g + c];
#pragma unroll
  for (int gg = 0; gg < 2; ++gg) {
    bias_xn[gg] = b_ih[64 + 16 * gg + c];
    bias_hn[gg] = b_hh[64 + 16 * gg + c];
  }
  float bq4[4], bk4[4], bv4[4];
#pragma unroll
  for (int g = 0; g < 4; ++g) {
    bq4[g] = b_query[16 * g + c];
    bk4[g] = b_key[16 * g + c];
    bv4[g] = b_value[16 * g + c];
  }
  float bo1 = b_out[c];
  float br0 = b_recall[0], br1 = b_recall[1];

  // --- recurrent state ---
  f32x4 hD0 = splat4(0.0f), hD1 = splat4(0.0f);  // h in C-layout (cols c, c+16)
  f32x4 keysR[3][4], valsR[3][4];                // memory slots, C-layout
#pragma unroll
  for (int s = 0; s < 3; ++s)
#pragma unroll
    for (int g = 0; g < 4; ++g) { keysR[s][g] = splat4(0.0f); valsR[s][g] = splat4(0.0f); }
  bf16x8 hA = *(const bf16x8*)&h_lds[c * 32 + 8 * q4];  // zeros

  // --- x prefetch (one step ahead) ---
  const float* xp = inputs + (size_t)(b0 + c) * (SL * NIN) + 8 * q4;
  f32x4 xA0 = *(const f32x4*)(xp + 0);
  f32x4 xA1 = *(const f32x4*)(xp + 4);
  f32x4 xB0 = *(const f32x4*)(xp + 32);
  f32x4 xB1 = *(const f32x4*)(xp + 36);

  float* outp = out_all + (size_t)(b0 + 4 * q4) * SL * NO + c;
  float* hidp = out_all + (size_t)NB * SL * NO + (size_t)(b0 + 4 * q4) * SL * NH + c;

#pragma unroll 1
  for (int t = 0; t < SL; ++t) {
    // convert prefetched x -> A-frags (chunk0 = k[0:32), chunk1 = k[32:64))
    bf16x8 ax0, ax1;
#pragma unroll
    for (int j = 0; j < 4; ++j) {
      ax0[j]     = (__bf16)xA0[j];
      ax0[4 + j] = (__bf16)xA1[j];
      ax1[j]     = (__bf16)xB0[j];
      ax1[4 + j] = (__bf16)xB1[j];
    }
    // issue next step's loads now (consumed next iteration)
    if (t + 1 < SL) {
      const float* xq = xp + (t + 1) * NIN;
      xA0 = *(const f32x4*)(xq + 0);
      xA1 = *(const f32x4*)(xq + 4);
      xB0 = *(const f32x4*)(xq + 32);
      xB1 = *(const f32x4*)(xq + 36);
    }
    // retr chunk A-frag (rows=batch, k0..1 = retr, rest zero)
    bf16x8 axr = *(const bf16x8*)&x2_lds[c * 32 + 8 * q4];

    // ---- GRU pre-activations: gx (+gh fused for r,z), separate hn ----
    f32x4 accRZ[4], accXN[2], accHN[2];
#pragma unroll
    for (int g = 0; g < 4; ++g) {
      f32x4 a = splat4(bias_rz[g]);
      a = MFMA(ax0, Bih[g][0], a);
      a = MFMA(ax1, Bih[g][1], a);
      a = MFMA(axr, Bih[g][2], a);
      a = MFMA(hA,  Bhh[g],    a);
      accRZ[g] = a;
    }
#pragma unroll
    for (int gg = 0; gg < 2; ++gg) {
      f32x4 a = splat4(bias_xn[gg]);
      a = MFMA(ax0, Bih[4 + gg][0], a);
      a = MFMA(ax1, Bih[4 + gg][1], a);
      a = MFMA(axr, Bih[4 + gg][2], a);
      accXN[gg] = a;
      f32x4 hsum = splat4(bias_hn[gg]);
      accHN[gg] = MFMA(hA, Bhh[4 + gg], hsum);
    }

    // ---- gates (elementwise, C-layout) ----
    f32x4 hn0, hn1;
#pragma unroll
    for (int r = 0; r < 4; ++r) {
      float rg0 = sigmoidf_(accRZ[0][r]);
      float zg0 = sigmoidf_(accRZ[2][r]);
      float ng0 = tanhf_(accXN[0][r] + rg0 * accHN[0][r]);
      float h0 = (1.0f - zg0) * ng0 + zg0 * hD0[r];
      float rg1 = sigmoidf_(accRZ[1][r]);
      float zg1 = sigmoidf_(accRZ[3][r]);
      float ng1 = tanhf_(accXN[1][r] + rg1 * accHN[1][r]);
      float h1 = (1.0f - zg1) * ng1 + zg1 * hD1[r];
      if (t == 3) { h0 = 0.0f; h1 = 0.0f; }  // flush exactly at t == MEMORY_SIZE
      hn0[r] = h0; hn1[r] = h1;
    }
    hD0 = hn0; hD1 = hn1;

    // hiddens store + C->A relay through LDS
#pragma unroll
    for (int r = 0; r < 4; ++r) {
      hidp[(r * SL + t) * NH]      = hn0[r];
      hidp[(r * SL + t) * NH + 16] = hn1[r];
      h_lds[(4 * q4 + r) * 32 + c]      = (__bf16)hn0[r];
      h_lds[(4 * q4 + r) * 32 + c + 16] = (__bf16)hn1[r];
    }
    hA = *(const bf16x8*)&h_lds[c * 32 + 8 * q4];  // in-wave order => coherent

    // ---- q / k_w / v_w / out projections (K=32, one MFMA each tile) ----
    f32x4 qT[4], kT[4], vT[4];
#pragma unroll
    for (int g = 0; g < 4; ++g) {
      qT[g] = MFMA(hA, Bq[g], splat4(bq4[g]));
      kT[g] = MFMA(hA, Bk[g], splat4(bk4[g]));
      vT[g] = MFMA(hA, Bv[g], splat4(bv4[g]));
    }
    f32x4 oT = MFMA(hA, Bo, splat4(bo1));

    // ---- attention over memory slots (uses keys/vals BEFORE this step's write) ----
    const int counter = (t < 3) ? t : 3;
    float sc[3][4];
#pragma unroll
    for (int s = 0; s < 3; ++s) {
#pragma unroll
      for (int r = 0; r < 4; ++r) {
        float p = qT[0][r] * keysR[s][0][r] + qT[1][r] * keysR[s][1][r] +
                  qT[2][r] * keysR[s][2][r] + qT[3][r] * keysR[s][3][r];
        p += __shfl_xor(p, 1);
        p += __shfl_xor(p, 2);
        p += __shfl_xor(p, 4);
        p += __shfl_xor(p, 8);
        sc[s][r] = p;
      }
    }
    float a0[4], a1[4], a2[4];
#pragma unroll
    for (int r = 0; r < 4; ++r) {
      float s0 = (counter > 0) ? sc[0][r] : -1e30f;
      float s1 = (counter > 1) ? sc[1][r] : -1e30f;
      float s2 = (counter > 2) ? sc[2][r] : -1e30f;
      float mx = fmaxf(s0, fmaxf(s1, s2));
      float e0 = __expf(s0 - mx), e1 = __expf(s1 - mx), e2 = __expf(s2 - mx);
      float inv = 1.0f / (e0 + e1 + e2);
      a0[r] = e0 * inv; a1[r] = e1 * inv; a2[r] = e2 * inv;
    }
    // read = attn . vals (in-lane), immediately folded into recall partials
    float p0[4], p1[4];
#pragma unroll
    for (int r = 0; r < 4; ++r) { p0[r] = 0.0f; p1[r] = 0.0f; }
#pragma unroll
    for (int g = 0; g < 4; ++g) {
#pragma unroll
      for (int r = 0; r < 4; ++r) {
        float rd = a0[r] * valsR[0][g][r] + a1[r] * valsR[1][g][r] +
                   a2[r] * valsR[2][g][r];
        p0[r] += rd * wr0f[g];
        p1[r] += rd * wr1f[g];
      }
    }
#pragma unroll
    for (int r = 0; r < 4; ++r) {
      float u0 = p0[r], u1 = p1[r];
      u0 += __shfl_xor(u0, 1); u0 += __shfl_xor(u0, 2);
      u0 += __shfl_xor(u0, 4); u0 += __shfl_xor(u0, 8);
      u1 += __shfl_xor(u1, 1); u1 += __shfl_xor(u1, 2);
      u1 += __shfl_xor(u1, 4); u1 += __shfl_xor(u1, 8);
      float r0 = (counter > 0) ? (u0 + br0) : 0.0f;
      float r1 = (counter > 0) ? (u1 + br1) : 0.0f;
      if (c == 0) {  // one writer lane per row group
        int row = 4 * q4 + r;
        x2_lds[row * 32]     = (__bf16)r0;
        x2_lds[row * 32 + 1] = (__bf16)r1;
      }
    }

    // ---- memory write (slot t, only while t < 3; after attention read) ----
    if (t == 0) {
#pragma unroll
      for (int g = 0; g < 4; ++g) { keysR[0][g] = kT[g]; valsR[0][g] = vT[g]; }
    } else if (t == 1) {
#pragma unroll
      for (int g = 0; g < 4; ++g) { keysR[1][g] = kT[g]; valsR[1][g] = vT[g]; }
    } else if (t == 2) {
#pragma unroll
      for (int g = 0; g < 4; ++g) { keysR[2][g] = kT[g]; valsR[2][g] = vT[g]; }
    }

    // ---- output store ----
#pragma unroll
    for (int r = 0; r < 4; ++r) outp[(r * SL + t) * NO] = oT[r];
  }
}

extern "C" void kernel_launch(void* const* d_in, const int* in_sizes, int n_in,
                              void* d_out, int out_size, void* d_ws, size_t ws_size,
                              hipStream_t stream) {
  (void)in_sizes; (void)n_in; (void)out_size; (void)d_ws; (void)ws_size;
  const float* inputs   = (const float*)d_in[0];
  const float* w_ih     = (const float*)d_in[1];
  const float* w_hh     = (const float*)d_in[2];
  const float* b_ih     = (const float*)d_in[3];
  const float* b_hh     = (const float*)d_in[4];
  const float* W_key    = (const float*)d_in[5];
  const float* b_key    = (const float*)d_in[6];
  const float* W_query  = (const float*)d_in[7];
  const float* b_query  = (const float*)d_in[8];
  const float* W_value  = (const float*)d_in[9];
  const float* b_value  = (const float*)d_in[10];
  const float* W_recall = (const float*)d_in[11];
  const float* b_recall = (const float*)d_in[12];
  const float* W_out    = (const float*)d_in[13];
  const float* b_out    = (const float*)d_in[14];
  float* out = (float*)d_out;

  kvmr_kernel<<<dim3(128), dim3(64), 0, stream>>>(
      inputs, w_ih, w_hh, b_ih, b_hh, W_key, b_key, W_query, b_query,
      W_value, b_value, W_recall, b_recall, W_out, b_out, out);
}

// Round 2
// 1311.824 us; speedup vs baseline: 1.6815x; 1.6815x over previous
//
#include <hip/hip_runtime.h>

// ---------------------------------------------------------------------------
// KeyValueMemoryRecallNet, R2: persistent weight-stationary MFMA recurrence
// with latency-optimized steady state.
//   - One wave (64 lanes) owns 16 batch rows for all 512 steps. 128 blocks.
//   - DPP row_ror add-reductions replace ds_bpermute shuffles.
//   - retr enters the GRU as an in-lane rank-2 FMA (no LDS relay, no MFMA).
//   - keys/vals freeze after t=2: fold M=keys@Wq, Cq=bq.keys, VR=vals.Wr^T
//     once; steady steps (t>=3) need no q/k/v MFMAs and no second reduction.
//   - h C->A LDS relay only feeds NEXT-step gh MFMAs (hPart carry) -> off the
//     attention critical path.
//
// MFMA 16x16x32 bf16 layouts (validated in R1):
//   A-frag: lane l holds A[row = l%16][k = 8*(l/16)+j]
//   B-frag: lane l holds B[k = 8*(l/16)+j][col = l%16]
//   C/D   : lane l holds D[row = 4*(l/16)+r][col = l%16]
// ---------------------------------------------------------------------------

typedef __attribute__((ext_vector_type(4))) float f32x4;
typedef __attribute__((ext_vector_type(8))) __bf16 bf16x8;

#define NB 2048
#define SL 512
#define NIN 64
#define NH 32
#define NO 16

__device__ __forceinline__ float sigmoidf_(float x) {
  return 1.0f / (1.0f + __expf(-x));
}
__device__ __forceinline__ float tanhf_(float x) {
  return 1.0f - 2.0f / (__expf(2.0f * x) + 1.0f);
}
__device__ __forceinline__ f32x4 splat4(float v) {
  f32x4 r; r[0] = v; r[1] = v; r[2] = v; r[3] = v; return r;
}

// DPP rotate-add reduction within each 16-lane row (groups == same l>>4).
template <int CTRL>
__device__ __forceinline__ float dpp_add_(float v) {
  int p = __builtin_amdgcn_update_dpp(0, __float_as_int(v), CTRL, 0xF, 0xF, true);
  return v + __int_as_float(p);
}
__device__ __forceinline__ float rowsum16(float v) {
  v = dpp_add_<0x121>(v);  // row_ror:1
  v = dpp_add_<0x122>(v);  // row_ror:2
  v = dpp_add_<0x124>(v);  // row_ror:4
  v = dpp_add_<0x128>(v);  // row_ror:8
  return v;
}

// B-frag of W^T (for y = x @ W^T): B[k][col] = W[col][k]. W row-major [out][in].
__device__ __forceinline__ bf16x8 ldfrag(const float* __restrict__ W, int indim,
                                         int row, int k0) {
  bf16x8 r;
#pragma unroll
  for (int j = 0; j < 8; ++j) {
    int k = k0 + j;
    float w = (k < indim) ? W[row * indim + k] : 0.0f;
    r[j] = (__bf16)w;
  }
  return r;
}
// B-frag of W (for y = x @ W): B[k][col] = W[k][col]. W row-major [K][ncol].
__device__ __forceinline__ bf16x8 ldfragT(const float* __restrict__ W, int ncol,
                                          int col, int k0) {
  bf16x8 r;
#pragma unroll
  for (int j = 0; j < 8; ++j) r[j] = (__bf16)W[(k0 + j) * ncol + col];
  return r;
}

#define MFMA(A, B, C) __builtin_amdgcn_mfma_f32_16x16x32_bf16((A), (B), (C), 0, 0, 0)

__global__ __launch_bounds__(64, 1)
void kvmr_kernel(const float* __restrict__ inputs,   // [2048][512][64]
                 const float* __restrict__ w_ih,     // [96][66]
                 const float* __restrict__ w_hh,     // [96][32]
                 const float* __restrict__ b_ih,     // [96]
                 const float* __restrict__ b_hh,     // [96]
                 const float* __restrict__ W_key,    // [64][32]
                 const float* __restrict__ b_key,    // [64]
                 const float* __restrict__ W_query,  // [64][32]
                 const float* __restrict__ b_query,  // [64]
                 const float* __restrict__ W_value,  // [64][32]
                 const float* __restrict__ b_value,  // [64]
                 const float* __restrict__ W_recall, // [2][64]
                 const float* __restrict__ b_recall, // [2]
                 const float* __restrict__ W_out,    // [16][32]
                 const float* __restrict__ b_out,    // [16]
                 float* __restrict__ out_all) {      // outputs | hiddens
  const int l  = threadIdx.x;
  const int c  = l & 15;
  const int q4 = l >> 4;
  const int b0 = blockIdx.x * 16;

  __shared__ __align__(16) __bf16 h_lds[16 * 32];       // h C->A relay
  __shared__ __align__(16) __bf16 kv_lds[3][16 * 64];   // fold-time keys relay

  // ---- weights as register-resident B-fragments ----
  bf16x8 Bih[6][2];  // gate tiles r0 r1 z0 z1 n0 n1; k-chunks x[0:32), x[32:64)
  bf16x8 Bhh[6];
#pragma unroll
  for (int g = 0; g < 6; ++g) {
#pragma unroll
    for (int kc = 0; kc < 2; ++kc)
      Bih[g][kc] = ldfrag(w_ih, 66, 16 * g + c, 32 * kc + 8 * q4);
    Bhh[g] = ldfrag(w_hh, 32, 16 * g + c, 8 * q4);
  }
  bf16x8 Bq[4], Bk[4], Bv[4];
#pragma unroll
  for (int g = 0; g < 4; ++g) {
    Bq[g] = ldfrag(W_query, 32, 16 * g + c, 8 * q4);
    Bk[g] = ldfrag(W_key,   32, 16 * g + c, 8 * q4);
    Bv[g] = ldfrag(W_value, 32, 16 * g + c, 8 * q4);
  }
  bf16x8 Bo = ldfrag(W_out, 32, c, 8 * q4);

  // retr rank-2 update coefficients: w_ih[:, 64] and w_ih[:, 65], col = 16g+c
  float wih64[6], wih65[6];
#pragma unroll
  for (int g = 0; g < 6; ++g) {
    wih64[g] = w_ih[(16 * g + c) * 66 + 64];
    wih65[g] = w_ih[(16 * g + c) * 66 + 65];
  }
  float wr0f[4], wr1f[4];
#pragma unroll
  for (int g = 0; g < 4; ++g) {
    wr0f[g] = W_recall[16 * g + c];
    wr1f[g] = W_recall[64 + 16 * g + c];
  }

  float bias_rz[4], bias_xn[2], bias_hn[2];
#pragma unroll
  for (int g = 0; g < 4; ++g) bias_rz[g] = b_ih[16 * g + c] + b_hh[16 * g + c];
#pragma unroll
  for (int gg = 0; gg < 2; ++gg) {
    bias_xn[gg] = b_ih[64 + 16 * gg + c];
    bias_hn[gg] = b_hh[64 + 16 * gg + c];
  }
  float bq4[4], bk4[4], bv4[4];
#pragma unroll
  for (int g = 0; g < 4; ++g) {
    bq4[g] = b_query[16 * g + c];
    bk4[g] = b_key[16 * g + c];
    bv4[g] = b_value[16 * g + c];
  }
  float bo1 = b_out[c];
  float br0 = b_recall[0], br1 = b_recall[1];

  // ---- state ----
  f32x4 hD0 = splat4(0.0f), hD1 = splat4(0.0f);
  f32x4 keysR[3][4], valsR[3][4];
#pragma unroll
  for (int s = 0; s < 3; ++s)
#pragma unroll
    for (int g = 0; g < 4; ++g) { keysR[s][g] = splat4(0.0f); valsR[s][g] = splat4(0.0f); }

  // software-pipelined carries
  f32x4 hPartRZ[4], hPartHN[2];
#pragma unroll
  for (int g = 0; g < 4; ++g) hPartRZ[g] = splat4(bias_rz[g]);
#pragma unroll
  for (int gg = 0; gg < 2; ++gg) hPartHN[gg] = splat4(bias_hn[gg]);
  float retr0c[4] = {0.f, 0.f, 0.f, 0.f};
  float retr1c[4] = {0.f, 0.f, 0.f, 0.f};

  // ---- x double prefetch ----
  const float* xp = inputs + (size_t)(b0 + c) * (SL * NIN) + 8 * q4;
  f32x4 xb[2][4];
#pragma unroll
  for (int p = 0; p < 2; ++p) {
    const float* xq = xp + p * NIN;
    xb[p][0] = *(const f32x4*)(xq + 0);
    xb[p][1] = *(const f32x4*)(xq + 4);
    xb[p][2] = *(const f32x4*)(xq + 32);
    xb[p][3] = *(const f32x4*)(xq + 36);
  }

  float* outp = out_all + (size_t)(b0 + 4 * q4) * SL * NO + c;
  float* hidp = out_all + (size_t)NB * SL * NO + (size_t)(b0 + 4 * q4) * SL * NH + c;

  // =========================================================================
  // Prologue: t = 0,1,2 (memory writes active; generic q/k/v path)
  // =========================================================================
#pragma unroll
  for (int t = 0; t < 3; ++t) {
    const int pb = t & 1;
    bf16x8 ax0, ax1;
#pragma unroll
    for (int j = 0; j < 4; ++j) {
      ax0[j]     = (__bf16)xb[pb][0][j];
      ax0[4 + j] = (__bf16)xb[pb][1][j];
      ax1[j]     = (__bf16)xb[pb][2][j];
      ax1[4 + j] = (__bf16)xb[pb][3][j];
    }
    {
      const float* xq = xp + (t + 2) * NIN;
      xb[pb][0] = *(const f32x4*)(xq + 0);
      xb[pb][1] = *(const f32x4*)(xq + 4);
      xb[pb][2] = *(const f32x4*)(xq + 32);
      xb[pb][3] = *(const f32x4*)(xq + 36);
    }

    f32x4 accRZ[4], accXN[2];
#pragma unroll
    for (int g = 0; g < 4; ++g) {
      f32x4 a = hPartRZ[g];
#pragma unroll
      for (int r = 0; r < 4; ++r) a[r] += retr0c[r] * wih64[g] + retr1c[r] * wih65[g];
      a = MFMA(ax0, Bih[g][0], a);
      a = MFMA(ax1, Bih[g][1], a);
      accRZ[g] = a;
    }
#pragma unroll
    for (int gg = 0; gg < 2; ++gg) {
      f32x4 a = splat4(bias_xn[gg]);
#pragma unroll
      for (int r = 0; r < 4; ++r) a[r] += retr0c[r] * wih64[4 + gg] + retr1c[r] * wih65[4 + gg];
      a = MFMA(ax0, Bih[4 + gg][0], a);
      a = MFMA(ax1, Bih[4 + gg][1], a);
      accXN[gg] = a;
    }

    f32x4 hn0, hn1;
#pragma unroll
    for (int r = 0; r < 4; ++r) {
      float rg0 = sigmoidf_(accRZ[0][r]);
      float zg0 = sigmoidf_(accRZ[2][r]);
      float ng0 = tanhf_(accXN[0][r] + rg0 * hPartHN[0][r]);
      hn0[r] = (1.0f - zg0) * ng0 + zg0 * hD0[r];
      float rg1 = sigmoidf_(accRZ[1][r]);
      float zg1 = sigmoidf_(accRZ[3][r]);
      float ng1 = tanhf_(accXN[1][r] + rg1 * hPartHN[1][r]);
      hn1[r] = (1.0f - zg1) * ng1 + zg1 * hD1[r];
    }
    hD0 = hn0; hD1 = hn1;

#pragma unroll
    for (int r = 0; r < 4; ++r) {
      hidp[(r * SL + t) * NH]      = hn0[r];
      hidp[(r * SL + t) * NH + 16] = hn1[r];
      h_lds[(4 * q4 + r) * 32 + c]      = (__bf16)hn0[r];
      h_lds[(4 * q4 + r) * 32 + c + 16] = (__bf16)hn1[r];
    }
    bf16x8 hA = *(const bf16x8*)&h_lds[c * 32 + 8 * q4];

#pragma unroll
    for (int g = 0; g < 4; ++g) hPartRZ[g] = MFMA(hA, Bhh[g], splat4(bias_rz[g]));
#pragma unroll
    for (int gg = 0; gg < 2; ++gg) hPartHN[gg] = MFMA(hA, Bhh[4 + gg], splat4(bias_hn[gg]));
    f32x4 oT = MFMA(hA, Bo, splat4(bo1));
#pragma unroll
    for (int r = 0; r < 4; ++r) outp[(r * SL + t) * NO] = oT[r];

    f32x4 qT[4], kT[4], vT[4];
#pragma unroll
    for (int g = 0; g < 4; ++g) {
      qT[g] = MFMA(hA, Bq[g], splat4(bq4[g]));
      kT[g] = MFMA(hA, Bk[g], splat4(bk4[g]));
      vT[g] = MFMA(hA, Bv[g], splat4(bv4[g]));
    }

    // attention over slots < t (scores on pre-write memory)
#pragma unroll
    for (int r = 0; r < 4; ++r) {
      float d0 = qT[0][r] * keysR[0][0][r] + qT[1][r] * keysR[0][1][r] +
                 qT[2][r] * keysR[0][2][r] + qT[3][r] * keysR[0][3][r];
      float d1 = qT[0][r] * keysR[1][0][r] + qT[1][r] * keysR[1][1][r] +
                 qT[2][r] * keysR[1][2][r] + qT[3][r] * keysR[1][3][r];
      float s0 = (t > 0) ? rowsum16(d0) : -1e30f;
      float s1 = (t > 1) ? rowsum16(d1) : -1e30f;
      float s2 = -1e30f;  // t<3 => slot2 never visible in prologue
      float mx = fmaxf(s0, fmaxf(s1, s2));
      float e0 = __expf(s0 - mx), e1 = __expf(s1 - mx), e2 = __expf(s2 - mx);
      float inv = 1.0f / (e0 + e1 + e2);
      float u0 = 0.f, u1 = 0.f;
#pragma unroll
      for (int g = 0; g < 4; ++g) {
        float rd = (e0 * valsR[0][g][r] + e1 * valsR[1][g][r] + e2 * valsR[2][g][r]) * inv;
        u0 += rd * wr0f[g];
        u1 += rd * wr1f[g];
      }
      u0 = rowsum16(u0);
      u1 = rowsum16(u1);
      retr0c[r] = (t > 0) ? (u0 + br0) : 0.0f;
      retr1c[r] = (t > 0) ? (u1 + br1) : 0.0f;
    }

    // write slot t
#pragma unroll
    for (int g = 0; g < 4; ++g) { keysR[t][g] = kT[g]; valsR[t][g] = vT[g]; }
  }

  // =========================================================================
  // Fold (memory frozen after t=2):
  //   M[s]  = keys[s] @ W_query        (per-batch effective score weights)
  //   Cq[s] = b_query . keys[s]        (score constant)
  //   VR[s] = vals[s] . W_recall^T     (pre-reduced recall contributions)
  // =========================================================================
#pragma unroll
  for (int s = 0; s < 3; ++s)
#pragma unroll
    for (int g = 0; g < 4; ++g)
#pragma unroll
      for (int r = 0; r < 4; ++r)
        kv_lds[s][(4 * q4 + r) * 64 + 16 * g + c] = (__bf16)keysR[s][g][r];

  bf16x8 Bwq[2][2];  // [kchunk][coltile], B = W_query ([64][32] row-major)
#pragma unroll
  for (int ch = 0; ch < 2; ++ch)
#pragma unroll
    for (int ct = 0; ct < 2; ++ct)
      Bwq[ch][ct] = ldfragT(W_query, 32, 16 * ct + c, 32 * ch + 8 * q4);

  float M0c[3][4], M1c[3][4], Cq[3][4], VRa[3][4], VRb[3][4];
#pragma unroll
  for (int s = 0; s < 3; ++s) {
    const bf16x8 ak0 = *(const bf16x8*)&kv_lds[s][c * 64 + 8 * q4];
    const bf16x8 ak1 = *(const bf16x8*)&kv_lds[s][c * 64 + 32 + 8 * q4];
    f32x4 m0 = MFMA(ak1, Bwq[1][0], MFMA(ak0, Bwq[0][0], splat4(0.0f)));
    f32x4 m1 = MFMA(ak1, Bwq[1][1], MFMA(ak0, Bwq[0][1], splat4(0.0f)));
#pragma unroll
    for (int r = 0; r < 4; ++r) {
      M0c[s][r] = m0[r];
      M1c[s][r] = m1[r];
      Cq[s][r] = rowsum16(keysR[s][0][r] * bq4[0] + keysR[s][1][r] * bq4[1] +
                          keysR[s][2][r] * bq4[2] + keysR[s][3][r] * bq4[3]);
      VRa[s][r] = rowsum16(valsR[s][0][r] * wr0f[0] + valsR[s][1][r] * wr0f[1] +
                           valsR[s][2][r] * wr0f[2] + valsR[s][3][r] * wr0f[3]);
      VRb[s][r] = rowsum16(valsR[s][0][r] * wr1f[0] + valsR[s][1][r] * wr1f[1] +
                           valsR[s][2][r] * wr1f[2] + valsR[s][3][r] * wr1f[3]);
    }
  }

  // =========================================================================
  // Steady state: t = 3..511 (no memory writes; folded attention)
  // =========================================================================
#pragma unroll 2
  for (int t = 3; t < SL; ++t) {
    const int pb = t & 1;
    bf16x8 ax0, ax1;
#pragma unroll
    for (int j = 0; j < 4; ++j) {
      ax0[j]     = (__bf16)xb[pb][0][j];
      ax0[4 + j] = (__bf16)xb[pb][1][j];
      ax1[j]     = (__bf16)xb[pb][2][j];
      ax1[4 + j] = (__bf16)xb[pb][3][j];
    }
    if (t + 2 < SL) {
      const float* xq = xp + (t + 2) * NIN;
      xb[pb][0] = *(const f32x4*)(xq + 0);
      xb[pb][1] = *(const f32x4*)(xq + 4);
      xb[pb][2] = *(const f32x4*)(xq + 32);
      xb[pb][3] = *(const f32x4*)(xq + 36);
    }

    f32x4 accRZ[4], accXN[2];
#pragma unroll
    for (int g = 0; g < 4; ++g) {
      f32x4 a = hPartRZ[g];
#pragma unroll
      for (int r = 0; r < 4; ++r) a[r] += retr0c[r] * wih64[g] + retr1c[r] * wih65[g];
      a = MFMA(ax0, Bih[g][0], a);
      a = MFMA(ax1, Bih[g][1], a);
      accRZ[g] = a;
    }
#pragma unroll
    for (int gg = 0; gg < 2; ++gg) {
      f32x4 a = splat4(bias_xn[gg]);
#pragma unroll
      for (int r = 0; r < 4; ++r) a[r] += retr0c[r] * wih64[4 + gg] + retr1c[r] * wih65[4 + gg];
      a = MFMA(ax0, Bih[4 + gg][0], a);
      a = MFMA(ax1, Bih[4 + gg][1], a);
      accXN[gg] = a;
    }

    f32x4 hn0, hn1;
#pragma unroll
    for (int r = 0; r < 4; ++r) {
      float rg0 = sigmoidf_(accRZ[0][r]);
      float zg0 = sigmoidf_(accRZ[2][r]);
      float ng0 = tanhf_(accXN[0][r] + rg0 * hPartHN[0][r]);
      float h0 = (1.0f - zg0) * ng0 + zg0 * hD0[r];
      float rg1 = sigmoidf_(accRZ[1][r]);
      float zg1 = sigmoidf_(accRZ[3][r]);
      float ng1 = tanhf_(accXN[1][r] + rg1 * hPartHN[1][r]);
      float h1 = (1.0f - zg1) * ng1 + zg1 * hD1[r];
      if (t == 3) { h0 = 0.0f; h1 = 0.0f; }  // flush exactly at t == MEMORY_SIZE
      hn0[r] = h0; hn1[r] = h1;
    }
    hD0 = hn0; hD1 = hn1;

    // hidden stores + h relay (relay feeds only next-step gh / out -> off path)
#pragma unroll
    for (int r = 0; r < 4; ++r) {
      hidp[(r * SL + t) * NH]      = hn0[r];
      hidp[(r * SL + t) * NH + 16] = hn1[r];
      h_lds[(4 * q4 + r) * 32 + c]      = (__bf16)hn0[r];
      h_lds[(4 * q4 + r) * 32 + c + 16] = (__bf16)hn1[r];
    }
    bf16x8 hA = *(const bf16x8*)&h_lds[c * 32 + 8 * q4];

#pragma unroll
    for (int g = 0; g < 4; ++g) hPartRZ[g] = MFMA(hA, Bhh[g], splat4(bias_rz[g]));
#pragma unroll
    for (int gg = 0; gg < 2; ++gg) hPartHN[gg] = MFMA(hA, Bhh[4 + gg], splat4(bias_hn[gg]));
    f32x4 oT = MFMA(hA, Bo, splat4(bo1));
#pragma unroll
    for (int r = 0; r < 4; ++r) outp[(r * SL + t) * NO] = oT[r];

    // folded attention: scores from C-layout h directly; counter == 3 (full)
#pragma unroll
    for (int r = 0; r < 4; ++r) {
      float p0 = hn0[r] * M0c[0][r] + hn1[r] * M1c[0][r];
      float p1 = hn0[r] * M0c[1][r] + hn1[r] * M1c[1][r];
      float p2 = hn0[r] * M0c[2][r] + hn1[r] * M1c[2][r];
      p0 = rowsum16(p0) + Cq[0][r];
      p1 = rowsum16(p1) + Cq[1][r];
      p2 = rowsum16(p2) + Cq[2][r];
      float mx = fmaxf(p0, fmaxf(p1, p2));
      float e0 = __expf(p0 - mx), e1 = __expf(p1 - mx), e2 = __expf(p2 - mx);
      float inv = 1.0f / (e0 + e1 + e2);
      retr0c[r] = br0 + (e0 * VRa[0][r] + e1 * VRa[1][r] + e2 * VRa[2][r]) * inv;
      retr1c[r] = br1 + (e0 * VRb[0][r] + e1 * VRb[1][r] + e2 * VRb[2][r]) * inv;
    }
  }
}

extern "C" void kernel_launch(void* const* d_in, const int* in_sizes, int n_in,
                              void* d_out, int out_size, void* d_ws, size_t ws_size,
                              hipStream_t stream) {
  (void)in_sizes; (void)n_in; (void)out_size; (void)d_ws; (void)ws_size;
  const float* inputs   = (const float*)d_in[0];
  const float* w_ih     = (const float*)d_in[1];
  const float* w_hh     = (const float*)d_in[2];
  const float* b_ih     = (const float*)d_in[3];
  const float* b_hh     = (const float*)d_in[4];
  const float* W_key    = (const float*)d_in[5];
  const float* b_key    = (const float*)d_in[6];
  const float* W_query  = (const float*)d_in[7];
  const float* b_query  = (const float*)d_in[8];
  const float* W_value  = (const float*)d_in[9];
  const float* b_value  = (const float*)d_in[10];
  const float* W_recall = (const float*)d_in[11];
  const float* b_recall = (const float*)d_in[12];
  const float* W_out    = (const float*)d_in[13];
  const float* b_out    = (const float*)d_in[14];
  float* out = (float*)d_out;

  kvmr_kernel<<<dim3(128), dim3(64), 0, stream>>>(
      inputs, w_ih, w_hh, b_ih, b_hh, W_key, b_key, W_query, b_query,
      W_value, b_value, W_recall, b_recall, W_out, b_out, out);
}